// Round 10
// baseline (297.558 us; speedup 1.0000x reference)
//
#include <hip/hip_runtime.h>
#include <stdint.h>

#define Bdim 4
#define Ldim 512
#define Hdim 768
#define Edim 10
#define Rdim 10

typedef __attribute__((ext_vector_type(8))) short short8;
typedef __attribute__((ext_vector_type(4))) float floatx4;

__device__ __forceinline__ unsigned short f2bf(float x) {
    unsigned int u = __float_as_uint(x);
    unsigned int r = (u + 0x7fffu + ((u >> 16) & 1u)) >> 16;
    return (unsigned short)r;
}
__device__ __forceinline__ float bf2f(unsigned short u) {
    return __uint_as_float(((unsigned int)u) << 16);
}

#define GLOAD_LDS16(g, l)                                                      \
    __builtin_amdgcn_global_load_lds(                                          \
        (const __attribute__((address_space(1))) void*)(g),                    \
        (__attribute__((address_space(3))) void*)(l), 16, 0, 0)

// bijective XCD remap of a linear block id (nwg must be %8==0)
__device__ __forceinline__ int xcd_swz(int bid, int nwg) {
    int cpx = nwg >> 3;
    return (bid & 7) * cpx + (bid >> 3);
}

// ===== 128^2 core, BK=64, SINGLE-buffer 32KB, m97-family 2-barrier sync =====
// 4 blocks/CU co-resident (LDS 32KB, <=128 VGPR, 4 waves/block): inter-block
// implicit overlap hides the drain (m114 mechanism). 3-bit XOR swizzle:
// chunk c of row r stored at physical chunk c^(r&7); linear LDS dest for
// global_load_lds via pre-swizzled global source; same XOR on ds_read.
__device__ __forceinline__ void gemm_bt_core128_sb(
    const unsigned short* __restrict__ A, int lda,
    const unsigned short* __restrict__ Bm, int ldb,
    unsigned short* lA, unsigned short* lB,
    floatx4 acc[4][4])
{
    const int tid  = threadIdx.x;       // 0..255
    const int lane = tid & 63;
    const int wave = tid >> 6;          // 0..3
    const int wr = wave >> 1;           // 0..1 (M)
    const int wc = wave & 1;            // 0..1 (N)
    const int frow = lane & 15;
    const int fs   = lane >> 4;         // 0..3

    const int NT = Hdim >> 6;           // 12
    for (int kt = 0; kt < NT; ++kt) {
        const int k0 = kt << 6;
        if (kt) __builtin_amdgcn_s_barrier();  // readers of tile kt-1 done
                                               // (their lgkm waits precede MFMA)
        #pragma unroll
        for (int i = 0; i < 4; ++i) {          // 8 gload_lds: A+B, 128 rows ea
            int q = tid + 256 * i, row = q >> 3, pchk = q & 7;
            int lchk = pchk ^ (row & 7);
            GLOAD_LDS16(A  + (size_t)row * lda + k0 + lchk * 8, lA + q * 8);
            GLOAD_LDS16(Bm + (size_t)row * ldb + k0 + lchk * 8, lB + q * 8);
        }
        __syncthreads();                       // vmcnt(0) drain: tile visible
        #pragma unroll
        for (int h = 0; h < 2; ++h) {
            short8 af[4], bfr[4];
            #pragma unroll
            for (int mi = 0; mi < 4; ++mi) {
                int row  = wr * 64 + mi * 16 + frow;
                int slot = (fs + 4 * h) ^ (row & 7);
                af[mi] = *reinterpret_cast<const short8*>(lA + row * 64 + slot * 8);
            }
            #pragma unroll
            for (int ni = 0; ni < 4; ++ni) {
                int row  = wc * 64 + ni * 16 + frow;
                int slot = (fs + 4 * h) ^ (row & 7);
                bfr[ni] = *reinterpret_cast<const short8*>(lB + row * 64 + slot * 8);
            }
            #pragma unroll
            for (int mi = 0; mi < 4; ++mi)
                #pragma unroll
                for (int ni = 0; ni < 4; ++ni)
                    acc[mi][ni] = __builtin_amdgcn_mfma_f32_16x16x32_bf16(
                        af[mi], bfr[ni], acc[mi][ni], 0, 0, 0);
        }
    }
}

// ================= k_prep: proj (f32-direct) + cvt(Wbil,We), fused ==========
__global__ __launch_bounds__(256) void k_prep(
    const float* __restrict__ h,   const float* __restrict__ Wp,
    const float* __restrict__ bproj,
    const float* __restrict__ Wbil, const float* __restrict__ We,
    unsigned short* __restrict__ hp,
    unsigned short* __restrict__ Wb_bf, unsigned short* __restrict__ We_bf)
{
    __shared__ unsigned short lA[128 * 64];
    __shared__ unsigned short lB[128 * 64];
    const int tid = threadIdx.x;

    if (blockIdx.x >= 96) {
        const int n2 = Rdim * Hdim * Hdim / 4;
        const int n3 = Edim * Hdim / 4;
        int i = (blockIdx.x - 96) * 256 + tid;
        const int stride = (gridDim.x - 96) * 256;
        for (; i < n2 + n3; i += stride) {
            const float* s; unsigned short* d; int j = i;
            if (j < n2) { s = Wbil; d = Wb_bf; }
            else { j -= n2; s = We; d = We_bf; }
            float4 v = reinterpret_cast<const float4*>(s)[j];
            ushort4 o;
            o.x = f2bf(v.x); o.y = f2bf(v.y); o.z = f2bf(v.z); o.w = f2bf(v.w);
            reinterpret_cast<ushort4*>(d)[j] = o;
        }
        return;
    }

    int bid = xcd_swz(blockIdx.x, 96);
    const int m0 = (bid % 16) * 128;
    const int n0 = (bid / 16) * 128;
    const float* Asrc = h  + (size_t)m0 * Hdim;
    const float* Bsrc = Wp + (size_t)n0 * Hdim;

    const int lane = tid & 63;
    const int wave = tid >> 6;
    const int wr = wave >> 1, wc = wave & 1;
    const int frow = lane & 15;
    const int fs   = lane >> 4;

    floatx4 acc[4][4];
    #pragma unroll
    for (int i = 0; i < 4; ++i)
        #pragma unroll
        for (int j = 0; j < 4; ++j)
            acc[i][j] = (floatx4){0.f, 0.f, 0.f, 0.f};

    float4 ra[4][2], rb[4][2];
    #define LOADREGS(k0s)                                                      \
        _Pragma("unroll")                                                      \
        for (int i = 0; i < 4; ++i) {                                          \
            int q = tid + 256 * i, row = q >> 3, pchk = q & 7;                 \
            int lchk = pchk ^ (row & 7);                                       \
            const float* sa = Asrc + (size_t)row * Hdim + (k0s) + lchk * 8;    \
            const float* sb = Bsrc + (size_t)row * Hdim + (k0s) + lchk * 8;    \
            ra[i][0] = *reinterpret_cast<const float4*>(sa);                   \
            ra[i][1] = *reinterpret_cast<const float4*>(sa + 4);               \
            rb[i][0] = *reinterpret_cast<const float4*>(sb);                   \
            rb[i][1] = *reinterpret_cast<const float4*>(sb + 4);               \
        }

    LOADREGS(0);
    const int NT = Hdim >> 6;    // 12
    for (int kt = 0; kt < NT; ++kt) {
        short8 pa[4], pb[4];
        #pragma unroll
        for (int i = 0; i < 4; ++i) {
            pa[i][0] = f2bf(ra[i][0].x); pa[i][1] = f2bf(ra[i][0].y);
            pa[i][2] = f2bf(ra[i][0].z); pa[i][3] = f2bf(ra[i][0].w);
            pa[i][4] = f2bf(ra[i][1].x); pa[i][5] = f2bf(ra[i][1].y);
            pa[i][6] = f2bf(ra[i][1].z); pa[i][7] = f2bf(ra[i][1].w);
            pb[i][0] = f2bf(rb[i][0].x); pb[i][1] = f2bf(rb[i][0].y);
            pb[i][2] = f2bf(rb[i][0].z); pb[i][3] = f2bf(rb[i][0].w);
            pb[i][4] = f2bf(rb[i][1].x); pb[i][5] = f2bf(rb[i][1].y);
            pb[i][6] = f2bf(rb[i][1].z); pb[i][7] = f2bf(rb[i][1].w);
        }
        __syncthreads();
        #pragma unroll
        for (int i = 0; i < 4; ++i) {
            int q = tid + 256 * i, row = q >> 3, pchk = q & 7;
            *reinterpret_cast<short8*>(lA + row * 64 + pchk * 8) = pa[i];
            *reinterpret_cast<short8*>(lB + row * 64 + pchk * 8) = pb[i];
        }
        if (kt + 1 < NT) LOADREGS((kt + 1) << 6);
        __syncthreads();
        #pragma unroll
        for (int hh = 0; hh < 2; ++hh) {
            short8 af[4], bfr[4];
            #pragma unroll
            for (int mi = 0; mi < 4; ++mi) {
                int row  = wr * 64 + mi * 16 + frow;
                int slot = (fs + 4 * hh) ^ (row & 7);
                af[mi] = *reinterpret_cast<const short8*>(lA + row * 64 + slot * 8);
            }
            #pragma unroll
            for (int ni = 0; ni < 4; ++ni) {
                int row  = wc * 64 + ni * 16 + frow;
                int slot = (fs + 4 * hh) ^ (row & 7);
                bfr[ni] = *reinterpret_cast<const short8*>(lB + row * 64 + slot * 8);
            }
            #pragma unroll
            for (int mi = 0; mi < 4; ++mi)
                #pragma unroll
                for (int ni = 0; ni < 4; ++ni)
                    acc[mi][ni] = __builtin_amdgcn_mfma_f32_16x16x32_bf16(
                        af[mi], bfr[ni], acc[mi][ni], 0, 0, 0);
        }
    }
    #undef LOADREGS

    const int cl = lane & 15, rh = (lane >> 4) * 4;
    #pragma unroll
    for (int mi = 0; mi < 4; ++mi)
        #pragma unroll
        for (int ni = 0; ni < 4; ++ni)
            #pragma unroll
            for (int j = 0; j < 4; ++j) {
                int r = m0 + wr * 64 + mi * 16 + rh + j;
                int c = n0 + wc * 64 + ni * 16 + cl;
                float v = acc[mi][ni][j] + bproj[c];
                hp[(size_t)r * Hdim + c] = f2bf(fmaxf(v, 0.0f));
            }
}

// ---- k_gemm_t_ent: ent (blocks 0..15, FIRST) + gemm_t 128^2 (16..975) ------
__global__ __launch_bounds__(256, 4) void k_gemm_t_ent(
    const unsigned short* __restrict__ hp,
    const unsigned short* __restrict__ Wb,
    unsigned short* __restrict__ T,
    const unsigned short* __restrict__ We,
    const float* __restrict__ bent,
    float* __restrict__ out_ent)
{
    __shared__ unsigned short lA[128 * 64];
    __shared__ unsigned short lB[128 * 64];
    const int tid = threadIdx.x, lane = tid & 63, wave = tid >> 6;

    if (blockIdx.x < 16) {
        // ---- ent: 16 blocks x 4 waves x 32 rows = 2048 rows ----
        const int base = (blockIdx.x * 4 + wave) * 32;
        for (int rr = 0; rr < 32; ++rr) {
            const unsigned short* row = hp + (size_t)(base + rr) * Hdim;
            float hv[12];
            #pragma unroll
            for (int j = 0; j < 12; ++j) hv[j] = bf2f(row[lane + j * 64]);
            #pragma unroll
            for (int ee = 0; ee < Edim; ++ee) {
                const unsigned short* wrow = We + ee * Hdim;
                float s = 0.f;
                #pragma unroll
                for (int j = 0; j < 12; ++j) s += hv[j] * bf2f(wrow[lane + j * 64]);
                #pragma unroll
                for (int off = 32; off >= 1; off >>= 1) s += __shfl_xor(s, off);
                if (lane == 0) out_ent[(size_t)(base + rr) * Edim + ee] = s + bent[ee];
            }
        }
        return;
    }

    int bid = xcd_swz(blockIdx.x - 16, 960);
    const int m0 = (bid % 16) * 128;
    const int n0 = (bid / 16) * 128;   // over R*H = 7680 (60 tiles)
    floatx4 acc[4][4];
    #pragma unroll
    for (int i = 0; i < 4; ++i)
        #pragma unroll
        for (int j = 0; j < 4; ++j)
            acc[i][j] = (floatx4){0.f, 0.f, 0.f, 0.f};

    gemm_bt_core128_sb(hp + (size_t)m0 * Hdim, Hdim,
                       Wb + (size_t)n0 * Hdim, Hdim, lA, lB, acc);

    const int wr = wave >> 1, wc = wave & 1;
    const int cl = lane & 15, rh = (lane >> 4) * 4;
    #pragma unroll
    for (int mi = 0; mi < 4; ++mi)
        #pragma unroll
        for (int ni = 0; ni < 4; ++ni)
            #pragma unroll
            for (int j = 0; j < 4; ++j) {
                int r = m0 + wr * 64 + mi * 16 + rh + j;
                int c = n0 + wc * 64 + ni * 16 + cl;
                T[(size_t)r * (Rdim * Hdim) + c] = f2bf(acc[mi][ni][j]);
            }
}

// ---- k_rel: 128^2 tiles, 640 blocks (~2.5 blocks/CU), N-merged output ------
__global__ __launch_bounds__(256, 4) void k_rel(
    const unsigned short* __restrict__ hp,
    const unsigned short* __restrict__ T,
    const float* __restrict__ bbil,
    float* __restrict__ rel)
{
    __shared__ unsigned short lA[128 * 64];
    __shared__ unsigned short lB[128 * 64];
    const int tid = threadIdx.x, lane = tid & 63, wave = tid >> 6;

    int bid = xcd_swz(blockIdx.x, 640);
    const int m0 = (bid % 16) * 128;          // global row over 2048
    const int n0 = (bid / 16) * 128;          // merged (m,r) over 5120 (40)
    const int b  = m0 >> 9;
    floatx4 acc[4][4];
    #pragma unroll
    for (int i = 0; i < 4; ++i)
        #pragma unroll
        for (int j = 0; j < 4; ++j)
            acc[i][j] = (floatx4){0.f, 0.f, 0.f, 0.f};

    const unsigned short* Ab = hp + (size_t)m0 * Hdim;
    const unsigned short* Bb = T + (size_t)b * Ldim * (Rdim * Hdim) + (size_t)n0 * Hdim;
    gemm_bt_core128_sb(Ab, Hdim, Bb, Hdim, lA, lB, acc);

    const int wr = wave >> 1, wc = wave & 1;
    const int cl = lane & 15, rh = (lane >> 4) * 4;
    #pragma unroll
    for (int mi = 0; mi < 4; ++mi)
        #pragma unroll
        for (int ni = 0; ni < 4; ++ni) {
            int n = n0 + wc * 64 + ni * 16 + cl;
            float bias = bbil[n % Rdim];
            #pragma unroll
            for (int j = 0; j < 4; ++j) {
                int grow = m0 + wr * 64 + mi * 16 + rh + j;
                rel[(size_t)grow * (Ldim * Rdim) + n] = acc[mi][ni][j] + bias;
            }
        }
}

extern "C" void kernel_launch(void* const* d_in, const int* in_sizes, int n_in,
                              void* d_out, int out_size, void* d_ws, size_t ws_size,
                              hipStream_t stream)
{
    const float* h     = (const float*)d_in[0];
    const float* Wproj = (const float*)d_in[1];
    const float* bproj = (const float*)d_in[2];
    const float* Went  = (const float*)d_in[3];
    const float* bent  = (const float*)d_in[4];
    const float* Wbil  = (const float*)d_in[5];
    const float* bbil  = (const float*)d_in[6];

    float* out_ent = (float*)d_out;
    float* out_rel = (float*)d_out + (size_t)Bdim * Ldim * Edim;

    unsigned short* Wb_bf = (unsigned short*)d_ws;
    unsigned short* We_bf = Wb_bf + (size_t)Rdim * Hdim * Hdim;
    unsigned short* hp_bf = We_bf + (size_t)Edim * Hdim;
    unsigned short* T_bf  = hp_bf + (size_t)2048 * Hdim;   // 2048 x 7680

    // 1) fused: proj (f32-direct, blocks 0..95) + cvt Wbil/We (96..1119)
    k_prep<<<dim3(1120), 256, 0, stream>>>(h, Wproj, bproj, Wbil, Went,
                                           hp_bf, Wb_bf, We_bf);

    // 2) ent (16 blocks, first) + gemm_t 128^2 (960 blocks, ~3.75/CU)
    k_gemm_t_ent<<<dim3(976), 256, 0, stream>>>(hp_bf, Wb_bf, T_bf,
                                                We_bf, bent, out_ent);

    // 3) rel: 128^2 tiles, 640 blocks (~2.5/CU)
    k_rel<<<dim3(640), 256, 0, stream>>>(hp_bf, T_bf, bbil, out_rel);
}